// Round 7
// baseline (218.438 us; speedup 1.0000x reference)
//
#include <hip/hip_runtime.h>

// RBF classifier: out = exp(-(||x-c||^2) * exp(-2*log_sigma)) @ W^T + b
// B=16384, D=784, C=2048, OUT=10. All fp32 in/out.
//
// R7: binder identified as per-CU VMEM instruction/return throughput
// (~64B/cyc). Fix = 2x arithmetic intensity per wave: 64x128 wave tile
// (128 AGPR acc), 128x256 block of 2x2 waves (A/B frags L1-shared by 2
// waves). Same load count per CU-iter as R6, twice the FLOP. Zero K-loop
// barriers, 1-iter prefetch, K pad 800 (25x32), grid (128,8) XCD-local.

#define B_ROWS 16384
#define D_DIM  784
#define C_DIM  2048
#define NOUT   10
#define NKC    25             // k-chunks of 32 (K padded 784->800)
#define NCG    128            // B col-groups of 16
#define LOG2E  1.4426950408889634f
#define PHLD   272            // Ph row stride (shorts): 544B = 16B-aligned, +8-bank quad offset

typedef __attribute__((ext_vector_type(8))) __bf16 bf16x8;
typedef __attribute__((ext_vector_type(4))) float  f32x4;
typedef __attribute__((ext_vector_type(4))) unsigned short ushort4v;

__device__ __forceinline__ unsigned short f2bf(float f) {
  union { float f; unsigned int u; } v; v.f = f;
  unsigned int u = v.u;
  return (unsigned short)((u + 0x7fffu + ((u >> 16) & 1u)) >> 16);  // RNE
}

// --- pack a (ROWS,784) fp32 matrix into MFMA fragment tiles via LDS
// transpose; one block per 16-row group. Coalesced float4 read -> bf16 LDS,
// then ds_read_b128 fragments, coalesced 1KB/wave global writes + squared
// norms (from bf16, consistent with the MFMA dot).
// A order: tile = g*NKC + kc. B order: tile = kc*(ROWS/16) + g.
template <int ROWS, int A_ORDER>
__global__ __launch_bounds__(256) void prep_pack(const float* __restrict__ src,
                                                 bf16x8* __restrict__ dst,
                                                 float* __restrict__ sq) {
  __shared__ unsigned short L[16 * 840];
  __shared__ float sqa[16];
  const int g = blockIdx.x;
  const int t = threadIdx.x;
  if (t < 16) sqa[t] = 0.f;
#pragma unroll
  for (int i = 0; i < 13; ++i) {            // 13*256 = 3328 = 16 rows * 208 ch
    const int chunk = t + 256 * i;
    const int row = chunk / 208;
    const int c4  = chunk % 208;
    const int k   = c4 * 4;
    ushort4v o = {0, 0, 0, 0};
    if (k + 4 <= D_DIM) {
      const float4 v = *(const float4*)(src + ((size_t)(g * 16 + row)) * D_DIM + k);
      o.x = f2bf(v.x); o.y = f2bf(v.y); o.z = f2bf(v.z); o.w = f2bf(v.w);
    }
    *(ushort4v*)&L[row * 840 + k] = o;
  }
  __syncthreads();
  const int w = t >> 6, lane = t & 63, q = lane >> 4, l16 = lane & 15;
  float part = 0.f;
  for (int i = 0; i < 7; ++i) {
    const int kc = w + 4 * i;
    if (kc < NKC) {
      union { bf16x8 v; __bf16 e[8]; } u;
      u.v = *(const bf16x8*)&L[l16 * 840 + kc * 32 + q * 8];
#pragma unroll
      for (int e = 0; e < 8; ++e) { const float x = (float)u.e[e]; part += x * x; }
      const size_t tile = A_ORDER ? ((size_t)g * NKC + kc)
                                  : ((size_t)kc * (ROWS / 16) + g);
      dst[tile * 64 + lane] = u.v;
    }
  }
  part += __shfl_down(part, 32);
  part += __shfl_down(part, 16);
  if (lane < 16) atomicAdd(&sqa[l16], part);
  __syncthreads();
  if (t < 16) sq[g * 16 + t] = sqa[t];
}

// fused tiny preps: out=bias | Wb bf16 (16,2048; rows 10..15 zero) | scale
// (pre-multiplied by log2(e) so epilogue uses exp2).
__global__ __launch_bounds__(256) void prep_misc(const float* __restrict__ ls,
                                                 const float* __restrict__ W,
                                                 const float* __restrict__ bias,
                                                 float* __restrict__ scale,
                                                 unsigned short* __restrict__ wb,
                                                 float* __restrict__ out) {
  const int i = blockIdx.x * 256 + threadIdx.x;
  if (i < B_ROWS * NOUT) out[i] = bias[i % NOUT];
  const int j = i - B_ROWS * NOUT;
  if (j >= 0 && j < 16 * C_DIM)
    wb[j] = ((j >> 11) < NOUT) ? f2bf(W[(j >> 11) * C_DIM + (j & 2047)]) : (unsigned short)0;
  const int k = j - 16 * C_DIM;
  if (k >= 0 && k < C_DIM) scale[k] = __expf(-2.f * ls[k]) * LOG2E;
}

// --- main: 128x256 block, 4 waves (2x2) each 64 rows x 128 cols.
// No K-loop LDS/barriers; operands stream global->VGPR, 1-iter prefetch.
__global__ __launch_bounds__(256, 2) void rbf_main(
    const bf16x8* __restrict__ apk, const bf16x8* __restrict__ cbp,
    const __bf16* __restrict__ wb,
    const float* __restrict__ x2, const float* __restrict__ c2,
    const float* __restrict__ scale, float* __restrict__ out) {
  __shared__ __bf16 Ph[128 * PHLD];   // 69,632 B
  __shared__ float x2s[128];

  const int tid  = threadIdx.x;
  const int w    = tid >> 6;
  const int lane = tid & 63;
  const int q    = lane >> 4;
  const int l16  = lane & 15;
  const int br   = blockIdx.x;        // 0..127 row block (128 rows) -> XCD=br%8
  const int bc   = blockIdx.y;        // 0..7   col block (256 cols)
  const int brow = br * 128;
  const int bcol = bc * 256;
  const int wr   = (w >> 1) * 64;     // wave row offset in block
  const int wc   = (w & 1) * 128;     // wave col offset in block

  if (tid < 128) x2s[tid] = x2[brow + tid];

  // A tiles: rg = br*8 + (wr>>4) + i, tile = rg*NKC + kc (i = 0..3).
  const bf16x8* apA = apk + ((size_t)(br * 8 + (w >> 1) * 4) * NKC) * 64 + lane;
  // B tiles: cg = bc*16 + (w&1)*8 + j, tile = kc*NCG + cg (j = 0..7).
  const bf16x8* cbw = cbp + ((size_t)(bc * 16 + (w & 1) * 8)) * 64 + lane;

  f32x4 acc[4][8] = {};
  bf16x8 afc[4], bfc[8], afn[4], bfn[8];
#pragma unroll
  for (int i = 0; i < 4; ++i) afc[i] = apA[(size_t)i * NKC * 64];
#pragma unroll
  for (int j = 0; j < 8; ++j) bfc[j] = cbw[(size_t)j * 64];

#pragma unroll 2
  for (int kc = 0; kc < NKC; ++kc) {
    const int kn = (kc + 1 < NKC) ? kc + 1 : NKC - 1;   // tail reload, L1 hit
#pragma unroll
    for (int i = 0; i < 4; ++i) afn[i] = apA[((size_t)i * NKC + kn) * 64];
#pragma unroll
    for (int j = 0; j < 8; ++j) bfn[j] = cbw[((size_t)kn * NCG + j) * 64];
#pragma unroll
    for (int i = 0; i < 4; ++i)
#pragma unroll
      for (int j = 0; j < 8; ++j)
        acc[i][j] = __builtin_amdgcn_mfma_f32_16x16x32_bf16(afc[i], bfc[j], acc[i][j], 0, 0, 0);
#pragma unroll
    for (int i = 0; i < 4; ++i) afc[i] = afn[i];
#pragma unroll
    for (int j = 0; j < 8; ++j) bfc[j] = bfn[j];
  }
  __syncthreads();   // x2s visible; all Ph writers aligned

  // epilogue 1: d2 -> phi -> Ph (bf16). C/D layout: col=lane&15, row=q*4+r.
#pragma unroll
  for (int i = 0; i < 4; ++i) {
    float xv[4];
#pragma unroll
    for (int r = 0; r < 4; ++r) xv[r] = x2s[wr + i * 16 + q * 4 + r];
#pragma unroll
    for (int j = 0; j < 8; ++j) {
      const int cl = wc + j * 16 + l16;              // 0..255
      const float c2v = c2[bcol + cl];
      const float sc = scale[bcol + cl];             // includes log2(e)
#pragma unroll
      for (int r = 0; r < 4; ++r) {
        const int rl = wr + i * 16 + q * 4 + r;      // 0..127
        const float d2 = fmaxf(fmaf(-2.f, acc[i][j][r], xv[r] + c2v), 0.f);
        Ph[rl * PHLD + cl] = (__bf16)__builtin_exp2f(-d2 * sc);
      }
    }
  }
  __syncthreads();

  // epilogue 2: out_tile(128x10) = Ph(128x256) @ Wb(16-row slice)^T, K=256.
  // wave w handles rows w*32..w*32+31 (2 m-frags).
  f32x4 oacc[2] = {};
#pragma unroll
  for (int kk = 0; kk < 8; ++kk) {
    const bf16x8 bw = *(const bf16x8*)&wb[(size_t)l16 * C_DIM + bcol + kk * 32 + q * 8];
#pragma unroll
    for (int mi = 0; mi < 2; ++mi) {
      const bf16x8 ap = *(const bf16x8*)&Ph[(w * 32 + mi * 16 + l16) * PHLD + kk * 32 + q * 8];
      oacc[mi] = __builtin_amdgcn_mfma_f32_16x16x32_bf16(ap, bw, oacc[mi], 0, 0, 0);
    }
  }
  if (l16 < NOUT) {
#pragma unroll
    for (int mi = 0; mi < 2; ++mi)
#pragma unroll
      for (int r = 0; r < 4; ++r) {
        const int grow = brow + w * 32 + mi * 16 + q * 4 + r;
        atomicAdd(&out[grow * NOUT + l16], oacc[mi][r]);
      }
  }
}

extern "C" void kernel_launch(void* const* d_in, const int* in_sizes, int n_in,
                              void* d_out, int out_size, void* d_ws, size_t ws_size,
                              hipStream_t stream) {
  const float* x    = (const float*)d_in[0];  // (16384,784)
  const float* cen  = (const float*)d_in[1];  // (2048,784)
  const float* ls   = (const float*)d_in[2];  // (2048,)
  const float* W    = (const float*)d_in[3];  // (10,2048)
  const float* bias = (const float*)d_in[4];  // (10,)
  float* out = (float*)d_out;                 // (16384,10)

  unsigned char* ws = (unsigned char*)d_ws;
  bf16x8* apk = (bf16x8*)(ws);                              // 1024*25 KB = 26,214,400
  bf16x8* cbp = (bf16x8*)(ws + 27262976);                   //  128*25 KB =  3,276,800
  unsigned short* wb = (unsigned short*)(ws + 30670848);    //  16*2048*2 =     65,536
  float* x2 = (float*)(ws + 30736384);                      // 16384*4
  float* c2 = (float*)(ws + 30801920);                      //  2048*4
  float* sc = (float*)(ws + 30810112);                      //  2048*4   (end 30,818,304)

  prep_pack<B_ROWS, 1><<<B_ROWS / 16, 256, 0, stream>>>(x, apk, x2);
  prep_pack<C_DIM, 0><<<C_DIM / 16, 256, 0, stream>>>(cen, cbp, c2);
  prep_misc<<<(B_ROWS * NOUT + 16 * C_DIM + C_DIM + 255) / 256, 256, 0, stream>>>(
      ls, W, bias, sc, wb, out);
  rbf_main<<<dim3(128, 8), 256, 0, stream>>>(apk, cbp, (const __bf16*)wb, x2, c2, sc, out);
}